// Round 6
// baseline (52.358 us; speedup 1.0000x reference)
//
#include <hip/hip_runtime.h>

#define B_DIM 8
#define T_DIM 16
#define H_IN 500
#define W_IN 500
#define NPH 127
#define NPW 127
#define LSTR 516      // 512+4 LDS row stride: transposed gathers stay ~2-way (free)
#define NT 512
#define BANDS 32      // 16-row bands per image
#define ROWS 16
#define MAXSPIN 65536

typedef float f4 __attribute__((ext_vector_type(4)));

// One block per (b, q): owns output rows [16q, 16q+16) and patches 4q..4q+3.
// Patches 4q..4q+2 are fully local. Patch 4q+3 needs neighbor rows
// 16(q+1)..16(q+1)+3: imported via a boundary buffer in ws (producer exports
// its rows 0..3 in Phase A, release-flag; consumer acquire-spins bounded,
// falls back to recomputing from input). Every patch cache line is written
// whole by exactly one block -> no partial-line write amplification.
__global__ __launch_bounds__(NT) void k_band(const float* __restrict__ in,
                                             const float* __restrict__ wgt,
                                             float* __restrict__ patches,
                                             float* __restrict__ crop,
                                             int* __restrict__ flags,
                                             float* __restrict__ bnd,
                                             int use_ws) {
    __shared__ float lds[(ROWS + 4) * LSTR];
    __shared__ f4 wlds[T_DIM * 4];       // weight[t][r][0..3]
    __shared__ int s_ready;
    int tid = threadIdx.x;
    if (tid < T_DIM * 4) wlds[tid] = reinterpret_cast<const f4*>(wgt)[tid];

    // XCD-chunk: b = orig&7 -> all 32 bands of one image share an XCD's L2,
    // so boundary exchange and flag traffic are L2-local.
    int orig = blockIdx.x;               // 256 blocks
    int b = orig & 7;
    int q = orig >> 3;                   // 0..31
    __syncthreads();

    // ---- Phase A: compute 16 rows x 512 cols into LDS (+ crop + export) ----
    #pragma unroll
    for (int k = 0; k < 4; ++k) {
        int e = tid + k * NT;            // 0..2047 f4 slots
        int r = e >> 7;                  // band row 0..15
        int c = (e & 127) * 4;           // col 0..508
        int h = q * ROWS + r;
        f4 acc = {0.f, 0.f, 0.f, 0.f};
        if (h < H_IN && c < W_IN) {      // 500 % 4 == 0: group-exact
            const float* base = in + (size_t)b * T_DIM * (H_IN * W_IN) + h * W_IN + c;
            int hr = h & 3;
            #pragma unroll
            for (int t = 0; t < T_DIM; ++t)
                acc += *reinterpret_cast<const f4*>(base + (size_t)t * (H_IN * W_IN))
                       * wlds[t * 4 + hr];
            *reinterpret_cast<f4*>(crop + ((size_t)b * H_IN + h) * W_IN + c) = acc;
        }
        *reinterpret_cast<f4*>(&lds[r * LSTR + c]) = acc;
        if (k == 0 && use_ws) {          // k==0 covers exactly rows 0..3
            *reinterpret_cast<f4*>(bnd + (size_t)(b * BANDS + q) * 2048 + r * 512 + c) = acc;
        }
    }
    __syncthreads();
    if (use_ws && tid == 0) {
        __threadfence();                                   // release export
        atomicExch(&flags[b * BANDS + q], 1);
    }

    // ---- Phase B-full: patches 4q, 4q+1, 4q+2 (all lines block-local) ----
    f4* pbase = reinterpret_cast<f4*>(patches)
              + ((size_t)b * NPH + (size_t)4 * q) * NPW * 16;
    for (int sub = 0; sub < 3; ++sub) {
        f4* dst = pbase + (size_t)sub * NPW * 16;
        for (int e4 = tid; e4 < NPW * 16; e4 += NT) {
            int i0 = (e4 & 1) * 4;
            int j  = (e4 >> 1) & 7;
            int pw = e4 >> 4;
            int col = pw * 4 + j;
            int r0 = sub * 4 + i0;
            f4 v;
            v.x = lds[(r0 + 0) * LSTR + col];
            v.y = lds[(r0 + 1) * LSTR + col];
            v.z = lds[(r0 + 2) * LSTR + col];
            v.w = lds[(r0 + 3) * LSTR + col];
            dst[e4] = v;
        }
    }

    // ---- Boundary patch 4q+3: import neighbor rows 0..3 (or recompute) ----
    if (q < BANDS - 1) {
        if (tid == 0) {
            int ok = 0;
            if (use_ws) {
                for (int it = 0; it < MAXSPIN; ++it) {
                    if (atomicAdd(&flags[b * BANDS + q + 1], 0) == 1) { ok = 1; break; }
                    __builtin_amdgcn_s_sleep(8);
                }
                if (ok) __threadfence();                   // acquire
            }
            s_ready = ok;
        }
        __syncthreads();
        {
            int r = tid >> 7;            // 0..3
            int c = (tid & 127) * 4;
            if (s_ready) {
                *reinterpret_cast<f4*>(&lds[(ROWS + r) * LSTR + c]) =
                    *reinterpret_cast<const f4*>(bnd + (size_t)(b * BANDS + q + 1) * 2048 + r * 512 + c);
            } else {
                int h = (q + 1) * ROWS + r;
                f4 acc = {0.f, 0.f, 0.f, 0.f};
                if (h < H_IN && c < W_IN) {
                    const float* base = in + (size_t)b * T_DIM * (H_IN * W_IN) + h * W_IN + c;
                    int hr = h & 3;
                    #pragma unroll
                    for (int t = 0; t < T_DIM; ++t)
                        acc += *reinterpret_cast<const f4*>(base + (size_t)t * (H_IN * W_IN))
                               * wlds[t * 4 + hr];
                }
                *reinterpret_cast<f4*>(&lds[(ROWS + r) * LSTR + c]) = acc;
            }
        }
        __syncthreads();
        f4* dst = pbase + (size_t)3 * NPW * 16;
        for (int e4 = tid; e4 < NPW * 16; e4 += NT) {
            int i0 = (e4 & 1) * 4;
            int j  = (e4 >> 1) & 7;
            int pw = e4 >> 4;
            int col = pw * 4 + j;
            int r0 = 12 + i0;            // i0=0 -> own rows 12..15; i0=4 -> imported 16..19
            f4 v;
            v.x = lds[(r0 + 0) * LSTR + col];
            v.y = lds[(r0 + 1) * LSTR + col];
            v.z = lds[(r0 + 2) * LSTR + col];
            v.w = lds[(r0 + 3) * LSTR + col];
            dst[e4] = v;
        }
    }
}

extern "C" void kernel_launch(void* const* d_in, const int* in_sizes, int n_in,
                              void* d_out, int out_size, void* d_ws, size_t ws_size,
                              hipStream_t stream) {
    const float* in  = (const float*)d_in[0];
    const float* wgt = (const float*)d_in[1];
    float* out     = (float*)d_out;
    float* patches = out;                                      // 8*16129*64 floats
    float* crop    = out + (size_t)B_DIM * NPH * NPW * 64;     // then 8*500*500

    size_t need = 256 * sizeof(int) + (size_t)256 * 2048 * sizeof(float);  // 1KB + 2MB
    int use_ws = (ws_size >= need) ? 1 : 0;
    int*   flags = (int*)d_ws;
    float* bnd   = (float*)d_ws + 256;

    if (use_ws) hipMemsetAsync(flags, 0, 256 * sizeof(int), stream);
    k_band<<<B_DIM * BANDS, NT, 0, stream>>>(in, wgt, patches, crop, flags, bnd, use_ws);
}

// Round 7
// 34.127 us; speedup vs baseline: 1.5342x; 1.5342x over previous
//
#include <hip/hip_runtime.h>

#define B_DIM 8
#define T_DIM 16
#define H_IN 500
#define W_IN 500
#define NPH 127
#define NPW 127
#define LSTR 516      // 512+4 LDS row stride: transposed gathers stay ~2-way (free)
#define NT 512
#define BANDS 32      // 16-row bands per image
#define ROWS 16
#define XROWS 20      // 16 own + 4 recomputed overlap rows

typedef float f4 __attribute__((ext_vector_type(4)));

// One block per (b, q): computes output rows [16q, 16q+20) (last 4 are the
// neighbor block's first rows, recomputed -- ~+25% logical input reads,
// mostly L3/L2-served since all bands of one b share an XCD). Owns patches
// 4q..4q+3 (4q..4q+2 for q=31) -- every patch cache line is written whole by
// exactly ONE block: no cross-block partial-line write amplification, and no
// inter-block synchronization.
__global__ __launch_bounds__(NT) void k_band(const float* __restrict__ in,
                                             const float* __restrict__ wgt,
                                             float* __restrict__ patches,
                                             float* __restrict__ crop) {
    __shared__ float lds[XROWS * LSTR];
    __shared__ f4 wlds[T_DIM * 4];       // weight[t][r][0..3]
    int tid = threadIdx.x;
    if (tid < T_DIM * 4) wlds[tid] = reinterpret_cast<const f4*>(wgt)[tid];

    // b = orig&7: all 32 bands of one image land on one XCD -> overlap-row
    // input lines are re-read from that XCD's L2, not HBM.
    int orig = blockIdx.x;               // 256 blocks
    int b = orig & 7;
    int q = orig >> 3;                   // 0..31
    __syncthreads();

    // ---- Phase A: compute 20 rows x 512 cols into LDS (+ crop for own 16) ----
    #pragma unroll
    for (int k = 0; k < 5; ++k) {
        int e = tid + k * NT;            // 0..2559 f4 slots
        int r = e >> 7;                  // band row 0..19
        int c = (e & 127) * 4;           // col 0..508
        int h = q * ROWS + r;
        f4 acc = {0.f, 0.f, 0.f, 0.f};
        if (h < H_IN && c < W_IN) {      // 500 % 4 == 0: group-exact
            const float* base = in + (size_t)b * T_DIM * (H_IN * W_IN) + h * W_IN + c;
            int hr = h & 3;
            #pragma unroll
            for (int t = 0; t < T_DIM; ++t)
                acc += *reinterpret_cast<const f4*>(base + (size_t)t * (H_IN * W_IN))
                       * wlds[t * 4 + hr];
            if (r < ROWS)
                *reinterpret_cast<f4*>(crop + ((size_t)b * H_IN + h) * W_IN + c) = acc;
        }
        *reinterpret_cast<f4*>(&lds[r * LSTR + c]) = acc;
    }
    __syncthreads();

    // ---- Phase B: patches 4q+s (s=0..3; 0..2 for q=31), all whole-line ----
    f4* pbase = reinterpret_cast<f4*>(patches)
              + ((size_t)b * NPH + (size_t)4 * q) * NPW * 16;
    int nsub = (q == BANDS - 1) ? 3 : 4;
    for (int sub = 0; sub < nsub; ++sub) {
        f4* dst = pbase + (size_t)sub * NPW * 16;
        for (int e4 = tid; e4 < NPW * 16; e4 += NT) {
            int i0 = (e4 & 1) * 4;
            int j  = (e4 >> 1) & 7;
            int pw = e4 >> 4;
            int col = pw * 4 + j;
            int r0 = sub * 4 + i0;       // band rows: sub*4 .. sub*4+7
            f4 v;
            v.x = lds[(r0 + 0) * LSTR + col];
            v.y = lds[(r0 + 1) * LSTR + col];
            v.z = lds[(r0 + 2) * LSTR + col];
            v.w = lds[(r0 + 3) * LSTR + col];
            dst[e4] = v;
        }
    }
}

extern "C" void kernel_launch(void* const* d_in, const int* in_sizes, int n_in,
                              void* d_out, int out_size, void* d_ws, size_t ws_size,
                              hipStream_t stream) {
    const float* in  = (const float*)d_in[0];
    const float* wgt = (const float*)d_in[1];
    float* out     = (float*)d_out;
    float* patches = out;                                      // 8*16129*64 floats
    float* crop    = out + (size_t)B_DIM * NPH * NPW * 64;     // then 8*500*500

    k_band<<<B_DIM * BANDS, NT, 0, stream>>>(in, wgt, patches, crop);
}

// Round 8
// 30.177 us; speedup vs baseline: 1.7350x; 1.1309x over previous
//
#include <hip/hip_runtime.h>

#define B_DIM 8
#define T_DIM 16
#define H_IN 500
#define W_IN 500
#define NPH 127
#define NPW 127
#define LSTR 516      // 512+4 LDS row stride: transposed gathers stay ~2-way (free)
#define NT 512
#define BANDS 32      // 16-row bands per image
#define ROWS 16

typedef float f4 __attribute__((ext_vector_type(4)));

// One block per (b, q): owns output rows [16q, 16q+16). Patches 4q..4q+2 are
// fully block-local (whole-line writes). Only patches ph = 4q+3 (31 of 127)
// are cross-block half-line interleaved:
//   - patch 4q+3, i=0..3 from own rows 12..15 (even f4 slots)
//   - patch 4q-1, i=4..7 from own rows 0..3   (odd  f4 slots)
// vs the 8-row-band version this halves the partial-line patch count with
// ZERO extra reads and ZERO synchronization.
__global__ __launch_bounds__(NT) void k_band(const float* __restrict__ in,
                                             const float* __restrict__ wgt,
                                             float* __restrict__ patches,
                                             float* __restrict__ crop) {
    __shared__ float lds[ROWS * LSTR];
    __shared__ f4 wlds[T_DIM * 4];       // weight[t][r][0..3]
    int tid = threadIdx.x;
    if (tid < T_DIM * 4) wlds[tid] = reinterpret_cast<const f4*>(wgt)[tid];

    // b = orig&7: all 32 bands of one image on one XCD -> the half-line
    // partners (bands q, q+1) share that XCD's L2 for write merging.
    int orig = blockIdx.x;               // 256 blocks
    int b = orig & 7;
    int q = orig >> 3;                   // 0..31
    __syncthreads();

    // ---- Phase A: compute 16 rows x 512 cols into LDS (+ crop write) ----
    #pragma unroll
    for (int k = 0; k < 4; ++k) {
        int e = tid + k * NT;            // 0..2047 f4 slots
        int r = e >> 7;                  // band row 0..15
        int c = (e & 127) * 4;           // col 0..508
        int h = q * ROWS + r;
        f4 acc = {0.f, 0.f, 0.f, 0.f};
        if (h < H_IN && c < W_IN) {      // 500 % 4 == 0: group-exact
            const float* base = in + (size_t)b * T_DIM * (H_IN * W_IN) + h * W_IN + c;
            int hr = h & 3;
            #pragma unroll
            for (int t = 0; t < T_DIM; ++t)
                acc += *reinterpret_cast<const f4*>(base + (size_t)t * (H_IN * W_IN))
                       * wlds[t * 4 + hr];
            *reinterpret_cast<f4*>(crop + ((size_t)b * H_IN + h) * W_IN + c) = acc;
        }
        *reinterpret_cast<f4*>(&lds[r * LSTR + c]) = acc;
    }
    __syncthreads();

    // ---- Phase B: full patches 4q, 4q+1, 4q+2 (whole-line stores) ----
    f4* pbase = reinterpret_cast<f4*>(patches)
              + ((size_t)b * NPH + (size_t)4 * q) * NPW * 16;
    #pragma unroll
    for (int sub = 0; sub < 3; ++sub) {
        f4* dst = pbase + (size_t)sub * NPW * 16;
        for (int e4 = tid; e4 < NPW * 16; e4 += NT) {
            int i0 = (e4 & 1) * 4;
            int j  = (e4 >> 1) & 7;
            int pw = e4 >> 4;
            int col = pw * 4 + j;
            int r0 = sub * 4 + i0;       // rows sub*4 .. sub*4+7
            f4 v;
            v.x = lds[(r0 + 0) * LSTR + col];
            v.y = lds[(r0 + 1) * LSTR + col];
            v.z = lds[(r0 + 2) * LSTR + col];
            v.w = lds[(r0 + 3) * LSTR + col];
            dst[e4] = v;
        }
    }
    // ---- Half patch ph=4q+3, i=0..3 (own rows 12..15, even f4 slots) ----
    if (q < BANDS - 1) {
        f4* dst = pbase + (size_t)3 * NPW * 16;
        for (int e = tid; e < NPW * 8; e += NT) {
            int j  = e & 7;
            int pw = e >> 3;
            int col = pw * 4 + j;
            f4 v;
            v.x = lds[12 * LSTR + col];
            v.y = lds[13 * LSTR + col];
            v.z = lds[14 * LSTR + col];
            v.w = lds[15 * LSTR + col];
            dst[pw * 16 + j * 2] = v;
        }
    }
    // ---- Half patch ph=4q-1, i=4..7 (own rows 0..3, odd f4 slots) ----
    if (q > 0) {
        f4* dst = reinterpret_cast<f4*>(patches)
                + ((size_t)b * NPH + (size_t)(4 * q - 1)) * NPW * 16;
        for (int e = tid; e < NPW * 8; e += NT) {
            int j  = e & 7;
            int pw = e >> 3;
            int col = pw * 4 + j;
            f4 v;
            v.x = lds[0 * LSTR + col];
            v.y = lds[1 * LSTR + col];
            v.z = lds[2 * LSTR + col];
            v.w = lds[3 * LSTR + col];
            dst[pw * 16 + j * 2 + 1] = v;
        }
    }
}

extern "C" void kernel_launch(void* const* d_in, const int* in_sizes, int n_in,
                              void* d_out, int out_size, void* d_ws, size_t ws_size,
                              hipStream_t stream) {
    const float* in  = (const float*)d_in[0];
    const float* wgt = (const float*)d_in[1];
    float* out     = (float*)d_out;
    float* patches = out;                                      // 8*16129*64 floats
    float* crop    = out + (size_t)B_DIM * NPH * NPW * 64;     // then 8*500*500

    k_band<<<B_DIM * BANDS, NT, 0, stream>>>(in, wgt, patches, crop);
}

// Round 9
// 29.844 us; speedup vs baseline: 1.7544x; 1.0112x over previous
//
#include <hip/hip_runtime.h>

#define B_DIM 8
#define T_DIM 16
#define H_IN 500
#define W_IN 500
#define NPH 127
#define NPW 127
#define LSTR 516      // 512+4 LDS row stride: transposed gathers stay ~2-way (free)
#define NT 512
#define BANDS 32      // 16-row bands per image
#define ROWS 16

typedef float f4 __attribute__((ext_vector_type(4)));

// One block per (b, q): owns output rows [16q, 16q+16). Patches 4q..4q+2 are
// fully block-local (whole-line writes); only ph=4q+3 (31 of 127) is
// cross-block interleaved (R8 structure, best so far).
// R9 change: Phase A batches ALL 16 t-plane loads into a register array
// before the FMA pass -> ~16 outstanding 16B loads per wave instead of the
// compiler's register-starved ~4-6, to cover HBM/L3 latency (Little's law).
__global__ __launch_bounds__(NT) void k_band(const float* __restrict__ in,
                                             const float* __restrict__ wgt,
                                             float* __restrict__ patches,
                                             float* __restrict__ crop) {
    __shared__ float lds[ROWS * LSTR];
    __shared__ f4 wlds[T_DIM * 4];       // weight[t][r][0..3]
    int tid = threadIdx.x;
    if (tid < T_DIM * 4) wlds[tid] = reinterpret_cast<const f4*>(wgt)[tid];

    // b = orig&7: all 32 bands of one image on one XCD -> half-line partner
    // blocks (bands q, q+1) share that XCD's L2 for write merging.
    int orig = blockIdx.x;               // 256 blocks
    int b = orig & 7;
    int q = orig >> 3;                   // 0..31
    __syncthreads();

    // ---- Phase A: compute 16 rows x 512 cols into LDS (+ crop write) ----
    #pragma unroll
    for (int k = 0; k < 4; ++k) {
        int e = tid + k * NT;            // 0..2047 f4 slots
        int r = e >> 7;                  // band row 0..15
        int c = (e & 127) * 4;           // col 0..508
        int h = q * ROWS + r;
        f4 acc = {0.f, 0.f, 0.f, 0.f};
        if (h < H_IN && c < W_IN) {      // 500 % 4 == 0: group-exact
            const float* base = in + (size_t)b * T_DIM * (H_IN * W_IN) + h * W_IN + c;
            int hr = h & 3;
            f4 xv[T_DIM];
            #pragma unroll
            for (int t = 0; t < T_DIM; ++t)   // 16 loads issued back-to-back
                xv[t] = *reinterpret_cast<const f4*>(base + (size_t)t * (H_IN * W_IN));
            #pragma unroll
            for (int t = 0; t < T_DIM; ++t)   // then the FMA pass
                acc += xv[t] * wlds[t * 4 + hr];
            *reinterpret_cast<f4*>(crop + ((size_t)b * H_IN + h) * W_IN + c) = acc;
        }
        *reinterpret_cast<f4*>(&lds[r * LSTR + c]) = acc;
    }
    __syncthreads();

    // ---- Phase B: full patches 4q, 4q+1, 4q+2 (whole-line stores) ----
    f4* pbase = reinterpret_cast<f4*>(patches)
              + ((size_t)b * NPH + (size_t)4 * q) * NPW * 16;
    #pragma unroll
    for (int sub = 0; sub < 3; ++sub) {
        f4* dst = pbase + (size_t)sub * NPW * 16;
        for (int e4 = tid; e4 < NPW * 16; e4 += NT) {
            int i0 = (e4 & 1) * 4;
            int j  = (e4 >> 1) & 7;
            int pw = e4 >> 4;
            int col = pw * 4 + j;
            int r0 = sub * 4 + i0;       // rows sub*4 .. sub*4+7
            f4 v;
            v.x = lds[(r0 + 0) * LSTR + col];
            v.y = lds[(r0 + 1) * LSTR + col];
            v.z = lds[(r0 + 2) * LSTR + col];
            v.w = lds[(r0 + 3) * LSTR + col];
            dst[e4] = v;
        }
    }
    // ---- Half patch ph=4q+3, i=0..3 (own rows 12..15, even f4 slots) ----
    if (q < BANDS - 1) {
        f4* dst = pbase + (size_t)3 * NPW * 16;
        for (int e = tid; e < NPW * 8; e += NT) {
            int j  = e & 7;
            int pw = e >> 3;
            int col = pw * 4 + j;
            f4 v;
            v.x = lds[12 * LSTR + col];
            v.y = lds[13 * LSTR + col];
            v.z = lds[14 * LSTR + col];
            v.w = lds[15 * LSTR + col];
            dst[pw * 16 + j * 2] = v;
        }
    }
    // ---- Half patch ph=4q-1, i=4..7 (own rows 0..3, odd f4 slots) ----
    if (q > 0) {
        f4* dst = reinterpret_cast<f4*>(patches)
                + ((size_t)b * NPH + (size_t)(4 * q - 1)) * NPW * 16;
        for (int e = tid; e < NPW * 8; e += NT) {
            int j  = e & 7;
            int pw = e >> 3;
            int col = pw * 4 + j;
            f4 v;
            v.x = lds[0 * LSTR + col];
            v.y = lds[1 * LSTR + col];
            v.z = lds[2 * LSTR + col];
            v.w = lds[3 * LSTR + col];
            dst[pw * 16 + j * 2 + 1] = v;
        }
    }
}

extern "C" void kernel_launch(void* const* d_in, const int* in_sizes, int n_in,
                              void* d_out, int out_size, void* d_ws, size_t ws_size,
                              hipStream_t stream) {
    const float* in  = (const float*)d_in[0];
    const float* wgt = (const float*)d_in[1];
    float* out     = (float*)d_out;
    float* patches = out;                                      // 8*16129*64 floats
    float* crop    = out + (size_t)B_DIM * NPH * NPW * 64;     // then 8*500*500

    k_band<<<B_DIM * BANDS, NT, 0, stream>>>(in, wgt, patches, crop);
}